// Round 1
// baseline (1590.079 us; speedup 1.0000x reference)
//
#include <hip/hip_runtime.h>
#include <hip/hip_bf16.h>

#define D 64

// tanh via native exp2: 1 - 2/(e^{2x}+1). Robust: x->+inf => e2=inf => 1; x->-inf => e2=0 => -1.
__device__ __forceinline__ float fast_tanh(float x) {
    float e2 = __expf(2.0f * x);
    return 1.0f - 2.0f / (e2 + 1.0f);
}

__device__ __forceinline__ float leaky(float x) {
    return x >= 0.0f ? x : 0.2f * x;
}

// ---------------- K1: h_trans = feat @ Watt^T + b  (N x 64) ----------------
__global__ __launch_bounds__(256) void k_htrans(const float* __restrict__ feat,
                                                const float* __restrict__ W,
                                                const float* __restrict__ bias,
                                                float* __restrict__ out, int N)
{
    __shared__ float Wt[D][D];       // Wt[d][c] = W[c*64+d]  (transposed for conflict-free reads)
    __shared__ float bsh[D];
    __shared__ float fs[32][D + 1];  // padded: broadcast rows hit distinct banks
    const int t = threadIdx.x;
    for (int i = t; i < D * D; i += 256) { Wt[i & 63][i >> 6] = W[i]; }
    if (t < D) bsh[t] = bias[t];
    const int cg = t & 15;   // column group (4 cols via float4)
    const int rp = t >> 4;   // row pair 0..15
    for (int g = 0; g < 2; ++g) {
        const int base = blockIdx.x * 64 + g * 32;
        __syncthreads();
        for (int i = t; i < 32 * D; i += 256) {
            int r = i >> 6, d = i & 63;
            int n = base + r;
            fs[r][d] = (n < N) ? feat[(size_t)n * D + d] : 0.0f;
        }
        __syncthreads();
        float4 acc0 = {0, 0, 0, 0}, acc1 = {0, 0, 0, 0};
        const int r0 = rp * 2, r1 = r0 + 1;
        #pragma unroll 8
        for (int d = 0; d < D; ++d) {
            const float4 w = *reinterpret_cast<const float4*>(&Wt[d][cg * 4]);
            const float f0 = fs[r0][d], f1 = fs[r1][d];
            acc0.x += f0 * w.x; acc0.y += f0 * w.y; acc0.z += f0 * w.z; acc0.w += f0 * w.w;
            acc1.x += f1 * w.x; acc1.y += f1 * w.y; acc1.z += f1 * w.z; acc1.w += f1 * w.w;
        }
        const float4 b4 = *reinterpret_cast<const float4*>(&bsh[cg * 4]);
        const int n0 = base + r0, n1 = base + r1;
        if (n0 < N) {
            float4 o = {acc0.x + b4.x, acc0.y + b4.y, acc0.z + b4.z, acc0.w + b4.w};
            *reinterpret_cast<float4*>(&out[(size_t)n0 * D + cg * 4]) = o;
        }
        if (n1 < N) {
            float4 o = {acc1.x + b4.x, acc1.y + b4.y, acc1.z + b4.z, acc1.w + b4.w};
            *reinterpret_cast<float4*>(&out[(size_t)n1 * D + cg * 4]) = o;
        }
    }
}

// ---------------- K2: per-edge score -> exp_e, denom (atomic) ----------------
// 16 lanes per edge; lane handles 4 d's (float4). No segment-max (softmax shift-invariant; fp32-safe range).
__global__ __launch_bounds__(256) void k_scores(const int* __restrict__ src,
                                                const int* __restrict__ dst,
                                                const float* __restrict__ ht,
                                                const float* __restrict__ er,
                                                float* __restrict__ exp_e,
                                                float* __restrict__ denom, int E)
{
    const int gid = blockIdx.x * 256 + threadIdx.x;
    const int lane = threadIdx.x & 15;
    const int e = gid >> 4;
    if (e >= E) return;
    const int s = src[e], dd = dst[e];
    const float4 hs = *reinterpret_cast<const float4*>(ht + (size_t)s * D + lane * 4);
    const float4 hd = *reinterpret_cast<const float4*>(ht + (size_t)dd * D + lane * 4);
    const float4 ev = *reinterpret_cast<const float4*>(er + (size_t)e * D + lane * 4);
    float p = hd.x * fast_tanh(hs.x + ev.x)
            + hd.y * fast_tanh(hs.y + ev.y)
            + hd.z * fast_tanh(hs.z + ev.z)
            + hd.w * fast_tanh(hs.w + ev.w);
    p += __shfl_xor(p, 1);
    p += __shfl_xor(p, 2);
    p += __shfl_xor(p, 4);
    p += __shfl_xor(p, 8);
    if (lane == 0) {
        const float x = p * 0.125f;               // 1/sqrt(64)
        const float eij = leaky(x);
        const float ex = __expf(eij);
        exp_e[e] = ex;
        unsafeAtomicAdd(&denom[dd], ex);
    }
}

// ---------------- K3: h_neigh[dst] += feat[src] * alpha ----------------
__global__ __launch_bounds__(256) void k_agg(const int* __restrict__ src,
                                             const int* __restrict__ dst,
                                             const float* __restrict__ feat,
                                             const float* __restrict__ exp_e,
                                             const float* __restrict__ denom,
                                             float* __restrict__ hneigh, int E)
{
    const int gid = blockIdx.x * 256 + threadIdx.x;
    const int lane = threadIdx.x & 15;
    const int e = gid >> 4;
    if (e >= E) return;
    const int s = src[e], dd = dst[e];
    const float a = exp_e[e] * __builtin_amdgcn_rcpf(denom[dd] + 1e-9f);
    const float4 f = *reinterpret_cast<const float4*>(feat + (size_t)s * D + lane * 4);
    float* o = hneigh + (size_t)dd * D + lane * 4;
    unsafeAtomicAdd(o + 0, a * f.x);
    unsafeAtomicAdd(o + 1, a * f.y);
    unsafeAtomicAdd(o + 2, a * f.z);
    unsafeAtomicAdd(o + 3, a * f.w);
}

// ---------------- K4: h_out = leaky((f+hn)@W1^T + b1 + (f*hn)@W2^T + b2) ----------------
__global__ __launch_bounds__(256) void k_out(const float* __restrict__ feat,
                                             const float* __restrict__ hneigh,
                                             const float* __restrict__ W1,
                                             const float* __restrict__ b1,
                                             const float* __restrict__ W2,
                                             const float* __restrict__ b2,
                                             float* __restrict__ out, int N)
{
    __shared__ float W1t[D][D];
    __shared__ float W2t[D][D];
    __shared__ float bsum[D];
    __shared__ float ss[32][D + 1];
    __shared__ float pp[32][D + 1];
    const int t = threadIdx.x;
    for (int i = t; i < D * D; i += 256) {
        W1t[i & 63][i >> 6] = W1[i];
        W2t[i & 63][i >> 6] = W2[i];
    }
    if (t < D) bsum[t] = b1[t] + b2[t];
    const int cg = t & 15;
    const int rp = t >> 4;
    for (int g = 0; g < 2; ++g) {
        const int base = blockIdx.x * 64 + g * 32;
        __syncthreads();
        for (int i = t; i < 32 * D; i += 256) {
            int r = i >> 6, d = i & 63;
            int n = base + r;
            float f = 0.0f, hn = 0.0f;
            if (n < N) { f = feat[(size_t)n * D + d]; hn = hneigh[(size_t)n * D + d]; }
            ss[r][d] = f + hn;
            pp[r][d] = f * hn;
        }
        __syncthreads();
        float4 a0 = {0, 0, 0, 0}, a1 = {0, 0, 0, 0};
        const int r0 = rp * 2, r1 = r0 + 1;
        #pragma unroll 4
        for (int d = 0; d < D; ++d) {
            const float4 w1 = *reinterpret_cast<const float4*>(&W1t[d][cg * 4]);
            const float4 w2 = *reinterpret_cast<const float4*>(&W2t[d][cg * 4]);
            const float s0 = ss[r0][d], p0 = pp[r0][d];
            const float s1 = ss[r1][d], p1 = pp[r1][d];
            a0.x += s0 * w1.x + p0 * w2.x; a0.y += s0 * w1.y + p0 * w2.y;
            a0.z += s0 * w1.z + p0 * w2.z; a0.w += s0 * w1.w + p0 * w2.w;
            a1.x += s1 * w1.x + p1 * w2.x; a1.y += s1 * w1.y + p1 * w2.y;
            a1.z += s1 * w1.z + p1 * w2.z; a1.w += s1 * w1.w + p1 * w2.w;
        }
        const float4 b4 = *reinterpret_cast<const float4*>(&bsum[cg * 4]);
        const int n0 = base + r0, n1 = base + r1;
        if (n0 < N) {
            float4 o = {leaky(a0.x + b4.x), leaky(a0.y + b4.y), leaky(a0.z + b4.z), leaky(a0.w + b4.w)};
            *reinterpret_cast<float4*>(&out[(size_t)n0 * D + cg * 4]) = o;
        }
        if (n1 < N) {
            float4 o = {leaky(a1.x + b4.x), leaky(a1.y + b4.y), leaky(a1.z + b4.z), leaky(a1.w + b4.w)};
            *reinterpret_cast<float4*>(&out[(size_t)n1 * D + cg * 4]) = o;
        }
    }
}

extern "C" void kernel_launch(void* const* d_in, const int* in_sizes, int n_in,
                              void* d_out, int out_size, void* d_ws, size_t ws_size,
                              hipStream_t stream) {
    const int*   idx  = (const int*)d_in[0];   // (2, E) int32
    const float* feat = (const float*)d_in[1]; // (N, 64)
    const float* er   = (const float*)d_in[2]; // (E, 64)
    const float* W1   = (const float*)d_in[4];
    const float* b1   = (const float*)d_in[5];
    const float* W2   = (const float*)d_in[6];
    const float* b2   = (const float*)d_in[7];
    const float* Wa   = (const float*)d_in[8];
    const float* ba   = (const float*)d_in[9];

    const int E = in_sizes[0] / 2;
    const int N = in_sizes[1] / D;
    const int* srcI = idx;
    const int* dstI = idx + E;

    // h_trans lives in d_out (N*64 floats, consumed by k_scores before k_out overwrites it).
    float* htrans = (float*)d_out;
    // ws layout: [h_neigh N*64 | denom N | exp_e E]  = 30.8 MB
    float* hneigh = (float*)d_ws;
    float* denom  = hneigh + (size_t)N * D;
    float* expe   = denom + N;

    hipMemsetAsync(hneigh, 0, (size_t)(N * D + N) * sizeof(float), stream);

    dim3 blk(256);
    k_htrans<<<dim3((N + 63) / 64), blk, 0, stream>>>(feat, Wa, ba, htrans, N);
    k_scores<<<dim3((E + 15) / 16), blk, 0, stream>>>(srcI, dstI, htrans, er, expe, denom, E);
    k_agg   <<<dim3((E + 15) / 16), blk, 0, stream>>>(srcI, dstI, feat, expe, denom, hneigh, E);
    k_out   <<<dim3((N + 63) / 64), blk, 0, stream>>>(feat, hneigh, W1, b1, W2, b2, (float*)d_out, N);
}

// Round 2
// 766.999 us; speedup vs baseline: 2.0731x; 2.0731x over previous
//
#include <hip/hip_runtime.h>
#include <hip/hip_bf16.h>

#define D 64
#define SCAN_CHUNK 2048   // 256 threads x 8 elements

// tanh via native exp: 1 - 2/(e^{2x}+1). Robust at +-inf.
__device__ __forceinline__ float fast_tanh(float x) {
    float e2 = __expf(2.0f * x);
    return 1.0f - 2.0f / (e2 + 1.0f);
}

__device__ __forceinline__ float leaky(float x) {
    return x >= 0.0f ? x : 0.2f * x;
}

// ---------------- K1: h_trans = feat @ Watt^T + b  (N x 64) ----------------
__global__ __launch_bounds__(256) void k_htrans(const float* __restrict__ feat,
                                                const float* __restrict__ W,
                                                const float* __restrict__ bias,
                                                float* __restrict__ out, int N)
{
    __shared__ float Wt[D][D];       // Wt[d][c] = W[c*64+d]
    __shared__ float bsh[D];
    __shared__ float fs[32][D + 1];
    const int t = threadIdx.x;
    for (int i = t; i < D * D; i += 256) { Wt[i & 63][i >> 6] = W[i]; }
    if (t < D) bsh[t] = bias[t];
    const int cg = t & 15;
    const int rp = t >> 4;
    for (int g = 0; g < 2; ++g) {
        const int base = blockIdx.x * 64 + g * 32;
        __syncthreads();
        for (int i = t; i < 32 * D; i += 256) {
            int r = i >> 6, d = i & 63;
            int n = base + r;
            fs[r][d] = (n < N) ? feat[(size_t)n * D + d] : 0.0f;
        }
        __syncthreads();
        float4 acc0 = {0, 0, 0, 0}, acc1 = {0, 0, 0, 0};
        const int r0 = rp * 2, r1 = r0 + 1;
        #pragma unroll 8
        for (int d = 0; d < D; ++d) {
            const float4 w = *reinterpret_cast<const float4*>(&Wt[d][cg * 4]);
            const float f0 = fs[r0][d], f1 = fs[r1][d];
            acc0.x += f0 * w.x; acc0.y += f0 * w.y; acc0.z += f0 * w.z; acc0.w += f0 * w.w;
            acc1.x += f1 * w.x; acc1.y += f1 * w.y; acc1.z += f1 * w.z; acc1.w += f1 * w.w;
        }
        const float4 b4 = *reinterpret_cast<const float4*>(&bsh[cg * 4]);
        const int n0 = base + r0, n1 = base + r1;
        if (n0 < N) {
            float4 o = {acc0.x + b4.x, acc0.y + b4.y, acc0.z + b4.z, acc0.w + b4.w};
            *reinterpret_cast<float4*>(&out[(size_t)n0 * D + cg * 4]) = o;
        }
        if (n1 < N) {
            float4 o = {acc1.x + b4.x, acc1.y + b4.y, acc1.z + b4.z, acc1.w + b4.w};
            *reinterpret_cast<float4*>(&out[(size_t)n1 * D + cg * 4]) = o;
        }
    }
}

// ---------------- counting sort: hist -> scan -> scatter ----------------
__global__ __launch_bounds__(256) void k_hist(const int* __restrict__ dst, int* __restrict__ cnt, int E)
{
    int e = blockIdx.x * 256 + threadIdx.x;
    if (e < E) atomicAdd(&cnt[dst[e]], 1);
}

// S1: per-chunk exclusive scan in place; chunk total -> partials[b]
__global__ __launch_bounds__(256) void k_scan1(int* __restrict__ offs, int* __restrict__ partials, int N)
{
    __shared__ int lds[256];
    const int t = threadIdx.x;
    const int base = blockIdx.x * SCAN_CHUNK + t * 8;
    int v[8];
    #pragma unroll
    for (int i = 0; i < 8; ++i) v[i] = (base + i < N) ? offs[base + i] : 0;
    int tot = 0;
    #pragma unroll
    for (int i = 0; i < 8; ++i) { int x = v[i]; v[i] = tot; tot += x; }
    lds[t] = tot;
    __syncthreads();
    for (int off = 1; off < 256; off <<= 1) {
        int x = 0;
        if (t >= off) x = lds[t - off];
        __syncthreads();
        lds[t] += x;
        __syncthreads();
    }
    const int texc = (t == 0) ? 0 : lds[t - 1];
    #pragma unroll
    for (int i = 0; i < 8; ++i)
        if (base + i < N) offs[base + i] = v[i] + texc;
    if (t == 255) partials[blockIdx.x] = lds[255];
}

// S2: serial exclusive scan of partials (NB <= ~64)
__global__ void k_scan2(int* __restrict__ partials, int NB)
{
    if (threadIdx.x == 0 && blockIdx.x == 0) {
        int run = 0;
        for (int i = 0; i < NB; ++i) { int x = partials[i]; partials[i] = run; run += x; }
    }
}

// S3: add chunk offsets
__global__ __launch_bounds__(256) void k_scan3(int* __restrict__ offs, const int* __restrict__ partials, int N)
{
    const int add = partials[blockIdx.x];
    if (add == 0) return;
    const int base = blockIdx.x * SCAN_CHUNK + threadIdx.x * 8;
    #pragma unroll
    for (int i = 0; i < 8; ++i)
        if (base + i < N) offs[base + i] += add;
}

// scatter edge ids into dst-sorted order. afterwards offs[i] = end of segment i.
__global__ __launch_bounds__(256) void k_scatter(const int* __restrict__ dst, int* __restrict__ offs,
                                                 int* __restrict__ eid, int E)
{
    int e = blockIdx.x * 256 + threadIdx.x;
    if (e < E) {
        int pos = atomicAdd(&offs[dst[e]], 1);
        eid[pos] = e;
    }
}

// ---------------- K_fused: per-dst gather: scores + softmax + aggregate ----------------
// 16 lanes per node; single pass: h_neigh = (sum ex*feat[src]) / (sum ex + 1e-9)
__global__ __launch_bounds__(256) void k_fused(const int* __restrict__ src,
                                               const int* __restrict__ eid,
                                               const int* __restrict__ offs,
                                               const float* __restrict__ ht,
                                               const float* __restrict__ er,
                                               const float* __restrict__ feat,
                                               float* __restrict__ hneigh, int N)
{
    const int t = threadIdx.x;
    const int lane = t & 15;
    const int n = blockIdx.x * 16 + (t >> 4);
    if (n >= N) return;
    const int beg = (n == 0) ? 0 : offs[n - 1];
    const int end = offs[n];
    const float4 hd = *reinterpret_cast<const float4*>(ht + (size_t)n * D + lane * 4);
    float4 acc = {0, 0, 0, 0};
    float den = 0.0f;
    for (int p = beg; p < end; ++p) {
        const int e = eid[p];
        const int s = src[e];
        const float4 hs = *reinterpret_cast<const float4*>(ht + (size_t)s * D + lane * 4);
        const float4 ev = *reinterpret_cast<const float4*>(er + (size_t)e * D + lane * 4);
        const float4 f  = *reinterpret_cast<const float4*>(feat + (size_t)s * D + lane * 4);
        float pp = hd.x * fast_tanh(hs.x + ev.x)
                 + hd.y * fast_tanh(hs.y + ev.y)
                 + hd.z * fast_tanh(hs.z + ev.z)
                 + hd.w * fast_tanh(hs.w + ev.w);
        pp += __shfl_xor(pp, 1);
        pp += __shfl_xor(pp, 2);
        pp += __shfl_xor(pp, 4);
        pp += __shfl_xor(pp, 8);
        const float ex = __expf(leaky(pp * 0.125f));
        den += ex;
        acc.x += ex * f.x; acc.y += ex * f.y; acc.z += ex * f.z; acc.w += ex * f.w;
    }
    const float r = __builtin_amdgcn_rcpf(den + 1e-9f);
    float4 o = {acc.x * r, acc.y * r, acc.z * r, acc.w * r};
    *reinterpret_cast<float4*>(hneigh + (size_t)n * D + lane * 4) = o;
}

// ---------------- K4: h_out = leaky((f+hn)@W1^T + b1 + (f*hn)@W2^T + b2) ----------------
__global__ __launch_bounds__(256) void k_out(const float* __restrict__ feat,
                                             const float* __restrict__ hneigh,
                                             const float* __restrict__ W1,
                                             const float* __restrict__ b1,
                                             const float* __restrict__ W2,
                                             const float* __restrict__ b2,
                                             float* __restrict__ out, int N)
{
    __shared__ float W1t[D][D];
    __shared__ float W2t[D][D];
    __shared__ float bsum[D];
    __shared__ float ss[32][D + 1];
    __shared__ float pp[32][D + 1];
    const int t = threadIdx.x;
    for (int i = t; i < D * D; i += 256) {
        W1t[i & 63][i >> 6] = W1[i];
        W2t[i & 63][i >> 6] = W2[i];
    }
    if (t < D) bsum[t] = b1[t] + b2[t];
    const int cg = t & 15;
    const int rp = t >> 4;
    for (int g = 0; g < 2; ++g) {
        const int base = blockIdx.x * 64 + g * 32;
        __syncthreads();
        for (int i = t; i < 32 * D; i += 256) {
            int r = i >> 6, d = i & 63;
            int n = base + r;
            float f = 0.0f, hn = 0.0f;
            if (n < N) { f = feat[(size_t)n * D + d]; hn = hneigh[(size_t)n * D + d]; }
            ss[r][d] = f + hn;
            pp[r][d] = f * hn;
        }
        __syncthreads();
        float4 a0 = {0, 0, 0, 0}, a1 = {0, 0, 0, 0};
        const int r0 = rp * 2, r1 = r0 + 1;
        #pragma unroll 4
        for (int d = 0; d < D; ++d) {
            const float4 w1 = *reinterpret_cast<const float4*>(&W1t[d][cg * 4]);
            const float4 w2 = *reinterpret_cast<const float4*>(&W2t[d][cg * 4]);
            const float s0 = ss[r0][d], p0 = pp[r0][d];
            const float s1 = ss[r1][d], p1 = pp[r1][d];
            a0.x += s0 * w1.x + p0 * w2.x; a0.y += s0 * w1.y + p0 * w2.y;
            a0.z += s0 * w1.z + p0 * w2.z; a0.w += s0 * w1.w + p0 * w2.w;
            a1.x += s1 * w1.x + p1 * w2.x; a1.y += s1 * w1.y + p1 * w2.y;
            a1.z += s1 * w1.z + p1 * w2.z; a1.w += s1 * w1.w + p1 * w2.w;
        }
        const float4 b4 = *reinterpret_cast<const float4*>(&bsum[cg * 4]);
        const int n0 = base + r0, n1 = base + r1;
        if (n0 < N) {
            float4 o = {leaky(a0.x + b4.x), leaky(a0.y + b4.y), leaky(a0.z + b4.z), leaky(a0.w + b4.w)};
            *reinterpret_cast<float4*>(&out[(size_t)n0 * D + cg * 4]) = o;
        }
        if (n1 < N) {
            float4 o = {leaky(a1.x + b4.x), leaky(a1.y + b4.y), leaky(a1.z + b4.z), leaky(a1.w + b4.w)};
            *reinterpret_cast<float4*>(&out[(size_t)n1 * D + cg * 4]) = o;
        }
    }
}

extern "C" void kernel_launch(void* const* d_in, const int* in_sizes, int n_in,
                              void* d_out, int out_size, void* d_ws, size_t ws_size,
                              hipStream_t stream) {
    const int*   idx  = (const int*)d_in[0];   // (2, E) int32
    const float* feat = (const float*)d_in[1]; // (N, 64)
    const float* er   = (const float*)d_in[2]; // (E, 64)
    const float* W1   = (const float*)d_in[4];
    const float* b1   = (const float*)d_in[5];
    const float* W2   = (const float*)d_in[6];
    const float* b2   = (const float*)d_in[7];
    const float* Wa   = (const float*)d_in[8];
    const float* ba   = (const float*)d_in[9];

    const int E = in_sizes[0] / 2;
    const int N = in_sizes[1] / D;
    const int* srcI = idx;
    const int* dstI = idx + E;

    // h_trans lives in d_out (consumed by k_fused before k_out overwrites it)
    float* htrans = (float*)d_out;
    // ws: [h_neigh N*64 f | offs N i | partials 256 i | eid_sorted E i]  ~30.8 MB
    float* hneigh   = (float*)d_ws;
    int*   offs     = (int*)(hneigh + (size_t)N * D);
    int*   partials = offs + N;
    int*   eid      = partials + 256;

    const int NB = (N + SCAN_CHUNK - 1) / SCAN_CHUNK;

    hipMemsetAsync(offs, 0, (size_t)N * sizeof(int), stream);

    dim3 blk(256);
    k_htrans <<<dim3((N + 63) / 64), blk, 0, stream>>>(feat, Wa, ba, htrans, N);
    k_hist   <<<dim3((E + 255) / 256), blk, 0, stream>>>(dstI, offs, E);
    k_scan1  <<<dim3(NB), blk, 0, stream>>>(offs, partials, N);
    k_scan2  <<<dim3(1), dim3(64), 0, stream>>>(partials, NB);
    k_scan3  <<<dim3(NB), blk, 0, stream>>>(offs, partials, N);
    k_scatter<<<dim3((E + 255) / 256), blk, 0, stream>>>(dstI, offs, eid, E);
    k_fused  <<<dim3((N + 15) / 16), blk, 0, stream>>>(srcI, eid, offs, htrans, er, feat, hneigh, N);
    k_out    <<<dim3((N + 63) / 64), blk, 0, stream>>>(feat, hneigh, W1, b1, W2, b2, (float*)d_out, N);
}

// Round 3
// 729.920 us; speedup vs baseline: 2.1784x; 1.0508x over previous
//
#include <hip/hip_runtime.h>
#include <hip/hip_bf16.h>

#define D 64
#define SCAN_CHUNK 2048   // 256 threads x 8 elements

// tanh via native exp: 1 - 2/(e^{2x}+1). Robust at +-inf.
__device__ __forceinline__ float fast_tanh(float x) {
    float e2 = __expf(2.0f * x);
    return 1.0f - 2.0f / (e2 + 1.0f);
}

__device__ __forceinline__ float leaky(float x) {
    return x >= 0.0f ? x : 0.2f * x;
}

// ---------------- K1: h_trans = feat @ Watt^T + b  (N x 64) ----------------
__global__ __launch_bounds__(256) void k_htrans(const float* __restrict__ feat,
                                                const float* __restrict__ W,
                                                const float* __restrict__ bias,
                                                float* __restrict__ out, int N)
{
    __shared__ float Wt[D][D];       // Wt[d][c] = W[c*64+d]
    __shared__ float bsh[D];
    __shared__ float fs[32][D + 1];
    const int t = threadIdx.x;
    for (int i = t; i < D * D; i += 256) { Wt[i & 63][i >> 6] = W[i]; }
    if (t < D) bsh[t] = bias[t];
    const int cg = t & 15;
    const int rp = t >> 4;
    for (int g = 0; g < 2; ++g) {
        const int base = blockIdx.x * 64 + g * 32;
        __syncthreads();
        for (int i = t; i < 32 * D; i += 256) {
            int r = i >> 6, d = i & 63;
            int n = base + r;
            fs[r][d] = (n < N) ? feat[(size_t)n * D + d] : 0.0f;
        }
        __syncthreads();
        float4 acc0 = {0, 0, 0, 0}, acc1 = {0, 0, 0, 0};
        const int r0 = rp * 2, r1 = r0 + 1;
        #pragma unroll 8
        for (int d = 0; d < D; ++d) {
            const float4 w = *reinterpret_cast<const float4*>(&Wt[d][cg * 4]);
            const float f0 = fs[r0][d], f1 = fs[r1][d];
            acc0.x += f0 * w.x; acc0.y += f0 * w.y; acc0.z += f0 * w.z; acc0.w += f0 * w.w;
            acc1.x += f1 * w.x; acc1.y += f1 * w.y; acc1.z += f1 * w.z; acc1.w += f1 * w.w;
        }
        const float4 b4 = *reinterpret_cast<const float4*>(&bsh[cg * 4]);
        const int n0 = base + r0, n1 = base + r1;
        if (n0 < N) {
            float4 o = {acc0.x + b4.x, acc0.y + b4.y, acc0.z + b4.z, acc0.w + b4.w};
            *reinterpret_cast<float4*>(&out[(size_t)n0 * D + cg * 4]) = o;
        }
        if (n1 < N) {
            float4 o = {acc1.x + b4.x, acc1.y + b4.y, acc1.z + b4.z, acc1.w + b4.w};
            *reinterpret_cast<float4*>(&out[(size_t)n1 * D + cg * 4]) = o;
        }
    }
}

// ---------------- counting sort: hist -> scan -> scatter ----------------
__global__ __launch_bounds__(256) void k_hist(const int* __restrict__ dst, int* __restrict__ cnt, int E)
{
    int e = blockIdx.x * 256 + threadIdx.x;
    if (e < E) atomicAdd(&cnt[dst[e]], 1);
}

__global__ __launch_bounds__(256) void k_scan1(int* __restrict__ offs, int* __restrict__ partials, int N)
{
    __shared__ int lds[256];
    const int t = threadIdx.x;
    const int base = blockIdx.x * SCAN_CHUNK + t * 8;
    int v[8];
    #pragma unroll
    for (int i = 0; i < 8; ++i) v[i] = (base + i < N) ? offs[base + i] : 0;
    int tot = 0;
    #pragma unroll
    for (int i = 0; i < 8; ++i) { int x = v[i]; v[i] = tot; tot += x; }
    lds[t] = tot;
    __syncthreads();
    for (int off = 1; off < 256; off <<= 1) {
        int x = 0;
        if (t >= off) x = lds[t - off];
        __syncthreads();
        lds[t] += x;
        __syncthreads();
    }
    const int texc = (t == 0) ? 0 : lds[t - 1];
    #pragma unroll
    for (int i = 0; i < 8; ++i)
        if (base + i < N) offs[base + i] = v[i] + texc;
    if (t == 255) partials[blockIdx.x] = lds[255];
}

__global__ void k_scan2(int* __restrict__ partials, int NB)
{
    if (threadIdx.x == 0 && blockIdx.x == 0) {
        int run = 0;
        for (int i = 0; i < NB; ++i) { int x = partials[i]; partials[i] = run; run += x; }
    }
}

__global__ __launch_bounds__(256) void k_scan3(int* __restrict__ offs, const int* __restrict__ partials, int N)
{
    const int add = partials[blockIdx.x];
    if (add == 0) return;
    const int base = blockIdx.x * SCAN_CHUNK + threadIdx.x * 8;
    #pragma unroll
    for (int i = 0; i < 8; ++i)
        if (base + i < N) offs[base + i] += add;
}

// scatter {edge id, src} into dst-sorted order. afterwards offs[i] = end of segment i.
__global__ __launch_bounds__(256) void k_scatter(const int* __restrict__ dst,
                                                 const int* __restrict__ srcA,
                                                 int* __restrict__ offs,
                                                 int2* __restrict__ es, int E)
{
    int e = blockIdx.x * 256 + threadIdx.x;
    if (e < E) {
        int pos = atomicAdd(&offs[dst[e]], 1);
        es[pos] = make_int2(e, srcA[e]);
    }
}

// ---------------- K_fused: wave per node, 4 edge-subgroups x 16 d-lanes ----------------
// h_neigh[n] = (sum_e ex*feat[src]) / (sum_e ex + 1e-9), ex = exp(leaky(score/8))
__global__ __launch_bounds__(256) void k_fused(const int2* __restrict__ es,
                                               const int* __restrict__ offs,
                                               const float* __restrict__ ht,
                                               const float* __restrict__ er,
                                               const float* __restrict__ feat,
                                               float* __restrict__ hneigh, int N)
{
    const int t = threadIdx.x;
    const int lane = t & 63;
    const int n = blockIdx.x * 4 + (t >> 6);
    if (n >= N) return;
    const int sg = lane >> 4;   // edge subgroup 0..3
    const int dl = lane & 15;   // d-lane: handles dims dl*4..dl*4+3
    const int beg = (n == 0) ? 0 : offs[n - 1];
    const int end = offs[n];
    const float4 hd = *reinterpret_cast<const float4*>(ht + (size_t)n * D + dl * 4);
    float4 acc = {0, 0, 0, 0};
    float den = 0.0f;
    int p = beg + sg;
    int2 cur = make_int2(0, 0);
    if (p < end) cur = es[p];
    while (p < end) {
        const int pn = p + 4;
        int2 nxt = make_int2(0, 0);
        if (pn < end) nxt = es[pn];               // prefetch next indices
        const float4 ev = *reinterpret_cast<const float4*>(er + (size_t)cur.x * D + dl * 4);
        const float4 hs = *reinterpret_cast<const float4*>(ht + (size_t)cur.y * D + dl * 4);
        const float4 f  = *reinterpret_cast<const float4*>(feat + (size_t)cur.y * D + dl * 4);
        float pp = hd.x * fast_tanh(hs.x + ev.x)
                 + hd.y * fast_tanh(hs.y + ev.y)
                 + hd.z * fast_tanh(hs.z + ev.z)
                 + hd.w * fast_tanh(hs.w + ev.w);
        pp += __shfl_xor(pp, 1);
        pp += __shfl_xor(pp, 2);
        pp += __shfl_xor(pp, 4);
        pp += __shfl_xor(pp, 8);
        const float ex = __expf(leaky(pp * 0.125f));
        den += ex;
        acc.x += ex * f.x; acc.y += ex * f.y; acc.z += ex * f.z; acc.w += ex * f.w;
        cur = nxt;
        p = pn;
    }
    // combine the 4 subgroups (lanes dl, dl+16, dl+32, dl+48)
    den += __shfl_xor(den, 16);
    den += __shfl_xor(den, 32);
    acc.x += __shfl_xor(acc.x, 16); acc.x += __shfl_xor(acc.x, 32);
    acc.y += __shfl_xor(acc.y, 16); acc.y += __shfl_xor(acc.y, 32);
    acc.z += __shfl_xor(acc.z, 16); acc.z += __shfl_xor(acc.z, 32);
    acc.w += __shfl_xor(acc.w, 16); acc.w += __shfl_xor(acc.w, 32);
    if (sg == 0) {
        const float r = __builtin_amdgcn_rcpf(den + 1e-9f);
        float4 o = {acc.x * r, acc.y * r, acc.z * r, acc.w * r};
        *reinterpret_cast<float4*>(hneigh + (size_t)n * D + dl * 4) = o;
    }
}

// ---------------- K4: h_out = leaky((f+hn)@W1^T + b1 + (f*hn)@W2^T + b2) ----------------
__global__ __launch_bounds__(256) void k_out(const float* __restrict__ feat,
                                             const float* __restrict__ hneigh,
                                             const float* __restrict__ W1,
                                             const float* __restrict__ b1,
                                             const float* __restrict__ W2,
                                             const float* __restrict__ b2,
                                             float* __restrict__ out, int N)
{
    __shared__ float W1t[D][D];
    __shared__ float W2t[D][D];
    __shared__ float bsum[D];
    __shared__ float ss[32][D + 1];
    __shared__ float pp[32][D + 1];
    const int t = threadIdx.x;
    for (int i = t; i < D * D; i += 256) {
        W1t[i & 63][i >> 6] = W1[i];
        W2t[i & 63][i >> 6] = W2[i];
    }
    if (t < D) bsum[t] = b1[t] + b2[t];
    const int cg = t & 15;
    const int rp = t >> 4;
    for (int g = 0; g < 2; ++g) {
        const int base = blockIdx.x * 64 + g * 32;
        __syncthreads();
        for (int i = t; i < 32 * D; i += 256) {
            int r = i >> 6, d = i & 63;
            int n = base + r;
            float f = 0.0f, hn = 0.0f;
            if (n < N) { f = feat[(size_t)n * D + d]; hn = hneigh[(size_t)n * D + d]; }
            ss[r][d] = f + hn;
            pp[r][d] = f * hn;
        }
        __syncthreads();
        float4 a0 = {0, 0, 0, 0}, a1 = {0, 0, 0, 0};
        const int r0 = rp * 2, r1 = r0 + 1;
        #pragma unroll 4
        for (int d = 0; d < D; ++d) {
            const float4 w1 = *reinterpret_cast<const float4*>(&W1t[d][cg * 4]);
            const float4 w2 = *reinterpret_cast<const float4*>(&W2t[d][cg * 4]);
            const float s0 = ss[r0][d], p0 = pp[r0][d];
            const float s1 = ss[r1][d], p1 = pp[r1][d];
            a0.x += s0 * w1.x + p0 * w2.x; a0.y += s0 * w1.y + p0 * w2.y;
            a0.z += s0 * w1.z + p0 * w2.z; a0.w += s0 * w1.w + p0 * w2.w;
            a1.x += s1 * w1.x + p1 * w2.x; a1.y += s1 * w1.y + p1 * w2.y;
            a1.z += s1 * w1.z + p1 * w2.z; a1.w += s1 * w1.w + p1 * w2.w;
        }
        const float4 b4 = *reinterpret_cast<const float4*>(&bsum[cg * 4]);
        const int n0 = base + r0, n1 = base + r1;
        if (n0 < N) {
            float4 o = {leaky(a0.x + b4.x), leaky(a0.y + b4.y), leaky(a0.z + b4.z), leaky(a0.w + b4.w)};
            *reinterpret_cast<float4*>(&out[(size_t)n0 * D + cg * 4]) = o;
        }
        if (n1 < N) {
            float4 o = {leaky(a1.x + b4.x), leaky(a1.y + b4.y), leaky(a1.z + b4.z), leaky(a1.w + b4.w)};
            *reinterpret_cast<float4*>(&out[(size_t)n1 * D + cg * 4]) = o;
        }
    }
}

extern "C" void kernel_launch(void* const* d_in, const int* in_sizes, int n_in,
                              void* d_out, int out_size, void* d_ws, size_t ws_size,
                              hipStream_t stream) {
    const int*   idx  = (const int*)d_in[0];   // (2, E) int32
    const float* feat = (const float*)d_in[1]; // (N, 64)
    const float* er   = (const float*)d_in[2]; // (E, 64)
    const float* W1   = (const float*)d_in[4];
    const float* b1   = (const float*)d_in[5];
    const float* W2   = (const float*)d_in[6];
    const float* b2   = (const float*)d_in[7];
    const float* Wa   = (const float*)d_in[8];
    const float* ba   = (const float*)d_in[9];

    const int E = in_sizes[0] / 2;
    const int N = in_sizes[1] / D;
    const int* srcI = idx;
    const int* dstI = idx + E;

    // h_trans lives in d_out (consumed by k_fused before k_out overwrites it)
    float* htrans = (float*)d_out;
    // ws: [h_neigh N*64 f | offs N i | partials 256 i | es E int2]  ~36 MB
    float* hneigh   = (float*)d_ws;
    int*   offs     = (int*)(hneigh + (size_t)N * D);
    int*   partials = offs + N;
    int2*  es       = (int2*)(partials + 256);

    const int NB = (N + SCAN_CHUNK - 1) / SCAN_CHUNK;

    hipMemsetAsync(offs, 0, (size_t)N * sizeof(int), stream);

    dim3 blk(256);
    k_htrans <<<dim3((N + 63) / 64), blk, 0, stream>>>(feat, Wa, ba, htrans, N);
    k_hist   <<<dim3((E + 255) / 256), blk, 0, stream>>>(dstI, offs, E);
    k_scan1  <<<dim3(NB), blk, 0, stream>>>(offs, partials, N);
    k_scan2  <<<dim3(1), dim3(64), 0, stream>>>(partials, NB);
    k_scan3  <<<dim3(NB), blk, 0, stream>>>(offs, partials, N);
    k_scatter<<<dim3((E + 255) / 256), blk, 0, stream>>>(dstI, srcI, offs, es, E);
    k_fused  <<<dim3((N + 3) / 4), blk, 0, stream>>>(es, offs, htrans, er, feat, hneigh, N);
    k_out    <<<dim3((N + 63) / 64), blk, 0, stream>>>(feat, hneigh, W1, b1, W2, b2, (float*)d_out, N);
}

// Round 5
// 717.346 us; speedup vs baseline: 2.2166x; 1.0175x over previous
//
#include <hip/hip_runtime.h>
#include <hip/hip_bf16.h>

#define D 64
#define SCAN_CHUNK 2048   // 256 threads x 8 elements

typedef unsigned int uint_t;
typedef unsigned short ushort_t;

// tanh via native exp: 1 - 2/(e^{2x}+1). Robust at +-inf.
__device__ __forceinline__ float fast_tanh(float x) {
    float e2 = __expf(2.0f * x);
    return 1.0f - 2.0f / (e2 + 1.0f);
}

__device__ __forceinline__ float leaky(float x) {
    return x >= 0.0f ? x : 0.2f * x;
}

// fp32 -> bf16 round-to-nearest-even
__device__ __forceinline__ ushort_t f2bf(float x) {
    uint_t u = __float_as_uint(x);
    u += 0x7FFFu + ((u >> 16) & 1u);
    return (ushort_t)(u >> 16);
}
__device__ __forceinline__ uint_t pack2bf(float lo, float hi) {
    return (uint_t)f2bf(lo) | ((uint_t)f2bf(hi) << 16);
}
// unpack 8 bf16 (uint4) -> 8 floats
__device__ __forceinline__ void bf8_unpack(uint4 u, float* f) {
    f[0] = __uint_as_float(u.x << 16); f[1] = __uint_as_float(u.x & 0xFFFF0000u);
    f[2] = __uint_as_float(u.y << 16); f[3] = __uint_as_float(u.y & 0xFFFF0000u);
    f[4] = __uint_as_float(u.z << 16); f[5] = __uint_as_float(u.z & 0xFFFF0000u);
    f[6] = __uint_as_float(u.w << 16); f[7] = __uint_as_float(u.w & 0xFFFF0000u);
}

// ---------------- K1: h_trans = feat @ Watt^T + b  -> bf16 table ----------------
__global__ __launch_bounds__(256) void k_htrans(const float* __restrict__ feat,
                                                const float* __restrict__ W,
                                                const float* __restrict__ bias,
                                                ushort_t* __restrict__ outB, int N)
{
    __shared__ float Wt[D][D];       // Wt[d][c] = W[c*64+d]
    __shared__ float bsh[D];
    __shared__ float fs[32][D + 1];
    const int t = threadIdx.x;
    for (int i = t; i < D * D; i += 256) { Wt[i & 63][i >> 6] = W[i]; }
    if (t < D) bsh[t] = bias[t];
    const int cg = t & 15;
    const int rp = t >> 4;
    for (int g = 0; g < 2; ++g) {
        const int base = blockIdx.x * 64 + g * 32;
        __syncthreads();
        for (int i = t; i < 32 * D; i += 256) {
            int r = i >> 6, d = i & 63;
            int n = base + r;
            fs[r][d] = (n < N) ? feat[(size_t)n * D + d] : 0.0f;
        }
        __syncthreads();
        float4 acc0 = {0, 0, 0, 0}, acc1 = {0, 0, 0, 0};
        const int r0 = rp * 2, r1 = r0 + 1;
        #pragma unroll 8
        for (int d = 0; d < D; ++d) {
            const float4 w = *reinterpret_cast<const float4*>(&Wt[d][cg * 4]);
            const float f0 = fs[r0][d], f1 = fs[r1][d];
            acc0.x += f0 * w.x; acc0.y += f0 * w.y; acc0.z += f0 * w.z; acc0.w += f0 * w.w;
            acc1.x += f1 * w.x; acc1.y += f1 * w.y; acc1.z += f1 * w.z; acc1.w += f1 * w.w;
        }
        const float4 b4 = *reinterpret_cast<const float4*>(&bsh[cg * 4]);
        const int n0 = base + r0, n1 = base + r1;
        if (n0 < N) {
            uint2 o = {pack2bf(acc0.x + b4.x, acc0.y + b4.y), pack2bf(acc0.z + b4.z, acc0.w + b4.w)};
            *reinterpret_cast<uint2*>(&outB[(size_t)n0 * D + cg * 4]) = o;
        }
        if (n1 < N) {
            uint2 o = {pack2bf(acc1.x + b4.x, acc1.y + b4.y), pack2bf(acc1.z + b4.z, acc1.w + b4.w)};
            *reinterpret_cast<uint2*>(&outB[(size_t)n1 * D + cg * 4]) = o;
        }
    }
}

// ---------------- feat f32 -> bf16 table ----------------
__global__ __launch_bounds__(256) void k_tobf(const float* __restrict__ in,
                                              ushort_t* __restrict__ out, int n8)
{
    int i = blockIdx.x * 256 + threadIdx.x;
    if (i >= n8) return;
    const float4 a = reinterpret_cast<const float4*>(in)[2 * i];
    const float4 b = reinterpret_cast<const float4*>(in)[2 * i + 1];
    uint4 o;
    o.x = pack2bf(a.x, a.y); o.y = pack2bf(a.z, a.w);
    o.z = pack2bf(b.x, b.y); o.w = pack2bf(b.z, b.w);
    reinterpret_cast<uint4*>(out)[i] = o;
}

// ---------------- counting sort: hist -> scan -> scatter ----------------
__global__ __launch_bounds__(256) void k_hist(const int* __restrict__ dst, int* __restrict__ cnt, int E)
{
    int e = blockIdx.x * 256 + threadIdx.x;
    if (e < E) atomicAdd(&cnt[dst[e]], 1);
}

__global__ __launch_bounds__(256) void k_scan1(int* __restrict__ offs, int* __restrict__ partials, int N)
{
    __shared__ int lds[256];
    const int t = threadIdx.x;
    const int base = blockIdx.x * SCAN_CHUNK + t * 8;
    int v[8];
    #pragma unroll
    for (int i = 0; i < 8; ++i) v[i] = (base + i < N) ? offs[base + i] : 0;
    int tot = 0;
    #pragma unroll
    for (int i = 0; i < 8; ++i) { int x = v[i]; v[i] = tot; tot += x; }
    lds[t] = tot;
    __syncthreads();
    for (int off = 1; off < 256; off <<= 1) {
        int x = 0;
        if (t >= off) x = lds[t - off];
        __syncthreads();
        lds[t] += x;
        __syncthreads();
    }
    const int texc = (t == 0) ? 0 : lds[t - 1];
    #pragma unroll
    for (int i = 0; i < 8; ++i)
        if (base + i < N) offs[base + i] = v[i] + texc;
    if (t == 255) partials[blockIdx.x] = lds[255];
}

__global__ void k_scan2(int* __restrict__ partials, int NB)
{
    if (threadIdx.x == 0 && blockIdx.x == 0) {
        int run = 0;
        for (int i = 0; i < NB; ++i) { int x = partials[i]; partials[i] = run; run += x; }
    }
}

__global__ __launch_bounds__(256) void k_scan3(int* __restrict__ offs, const int* __restrict__ partials, int N)
{
    const int add = partials[blockIdx.x];
    if (add == 0) return;
    const int base = blockIdx.x * SCAN_CHUNK + threadIdx.x * 8;
    #pragma unroll
    for (int i = 0; i < 8; ++i)
        if (base + i < N) offs[base + i] += add;
}

// scatter {edge id, src} into dst-sorted order. afterwards offs[i] = end of segment i.
__global__ __launch_bounds__(256) void k_scatter(const int* __restrict__ dst,
                                                 const int* __restrict__ srcA,
                                                 int* __restrict__ offs,
                                                 int2* __restrict__ es, int E)
{
    int e = blockIdx.x * 256 + threadIdx.x;
    if (e < E) {
        int pos = atomicAdd(&offs[dst[e]], 1);
        es[pos] = make_int2(e, srcA[e]);
    }
}

// ---------------- K_fused: wave per node, 8 edge-subgroups x 8 d-lanes ----------------
// h_neigh[n] = (sum_e ex*feat[src]) / (sum_e ex + 1e-9), ex = exp(leaky(score/8))
__global__ __launch_bounds__(256) void k_fused(const int2* __restrict__ es,
                                               const int* __restrict__ offs,
                                               const ushort_t* __restrict__ htB,
                                               const float* __restrict__ er,
                                               const ushort_t* __restrict__ featB,
                                               float* __restrict__ hneigh, int N)
{
    const int t = threadIdx.x;
    const int lane = t & 63;
    const int n = blockIdx.x * 4 + (t >> 6);
    if (n >= N) return;
    const int sg = lane >> 3;   // edge subgroup 0..7
    const int dl = lane & 7;    // d-lane: dims dl*8 .. dl*8+7
    const int beg = (n == 0) ? 0 : offs[n - 1];
    const int end = offs[n];
    float hd[8];
    bf8_unpack(*reinterpret_cast<const uint4*>(htB + (size_t)n * D + dl * 8), hd);
    float acc[8] = {0, 0, 0, 0, 0, 0, 0, 0};
    float den = 0.0f;
    int p = beg + sg;
    int2 cur = make_int2(0, 0);
    if (p < end) cur = es[p];
    while (p < end) {
        const int pn = p + 8;
        int2 nxt = make_int2(0, 0);
        if (pn < end) nxt = es[pn];               // prefetch next indices
        float hs[8], f[8];
        bf8_unpack(*reinterpret_cast<const uint4*>(htB + (size_t)cur.y * D + dl * 8), hs);
        bf8_unpack(*reinterpret_cast<const uint4*>(featB + (size_t)cur.y * D + dl * 8), f);
        const float4 e0 = *reinterpret_cast<const float4*>(er + (size_t)cur.x * D + dl * 8);
        const float4 e1 = *reinterpret_cast<const float4*>(er + (size_t)cur.x * D + dl * 8 + 4);
        float s = hd[0] * fast_tanh(hs[0] + e0.x)
                + hd[1] * fast_tanh(hs[1] + e0.y)
                + hd[2] * fast_tanh(hs[2] + e0.z)
                + hd[3] * fast_tanh(hs[3] + e0.w)
                + hd[4] * fast_tanh(hs[4] + e1.x)
                + hd[5] * fast_tanh(hs[5] + e1.y)
                + hd[6] * fast_tanh(hs[6] + e1.z)
                + hd[7] * fast_tanh(hs[7] + e1.w);
        s += __shfl_xor(s, 1);
        s += __shfl_xor(s, 2);
        s += __shfl_xor(s, 4);
        const float ex = __expf(leaky(s * 0.125f));
        den += ex;
        #pragma unroll
        for (int j = 0; j < 8; ++j) acc[j] += ex * f[j];
        cur = nxt;
        p = pn;
    }
    // combine the 8 subgroups (lanes dl, dl+8, ..., dl+56)
    #pragma unroll
    for (int m = 8; m <= 32; m <<= 1) {
        den += __shfl_xor(den, m);
        #pragma unroll
        for (int j = 0; j < 8; ++j) acc[j] += __shfl_xor(acc[j], m);
    }
    if (sg == 0) {
        const float r = __builtin_amdgcn_rcpf(den + 1e-9f);
        float4 o0 = {acc[0] * r, acc[1] * r, acc[2] * r, acc[3] * r};
        float4 o1 = {acc[4] * r, acc[5] * r, acc[6] * r, acc[7] * r};
        *reinterpret_cast<float4*>(hneigh + (size_t)n * D + dl * 8) = o0;
        *reinterpret_cast<float4*>(hneigh + (size_t)n * D + dl * 8 + 4) = o1;
    }
}

// ---------------- K4: h_out = leaky((f+hn)@W1^T + b1 + (f*hn)@W2^T + b2) ----------------
__global__ __launch_bounds__(256) void k_out(const float* __restrict__ feat,
                                             const float* __restrict__ hneigh,
                                             const float* __restrict__ W1,
                                             const float* __restrict__ b1,
                                             const float* __restrict__ W2,
                                             const float* __restrict__ b2,
                                             float* __restrict__ out, int N)
{
    __shared__ float W1t[D][D];
    __shared__ float W2t[D][D];
    __shared__ float bsum[D];
    __shared__ float ss[32][D + 1];
    __shared__ float pp[32][D + 1];
    const int t = threadIdx.x;
    for (int i = t; i < D * D; i += 256) {
        W1t[i & 63][i >> 6] = W1[i];
        W2t[i & 63][i >> 6] = W2[i];
    }
    if (t < D) bsum[t] = b1[t] + b2[t];
    const int cg = t & 15;
    const int rp = t >> 4;
    for (int g = 0; g < 2; ++g) {
        const int base = blockIdx.x * 64 + g * 32;
        __syncthreads();
        for (int i = t; i < 32 * D; i += 256) {
            int r = i >> 6, d = i & 63;
            int n = base + r;
            float f = 0.0f, hn = 0.0f;
            if (n < N) { f = feat[(size_t)n * D + d]; hn = hneigh[(size_t)n * D + d]; }
            ss[r][d] = f + hn;
            pp[r][d] = f * hn;
        }
        __syncthreads();
        float4 a0 = {0, 0, 0, 0}, a1 = {0, 0, 0, 0};
        const int r0 = rp * 2, r1 = r0 + 1;
        #pragma unroll 4
        for (int d = 0; d < D; ++d) {
            const float4 w1 = *reinterpret_cast<const float4*>(&W1t[d][cg * 4]);
            const float4 w2 = *reinterpret_cast<const float4*>(&W2t[d][cg * 4]);
            const float s0 = ss[r0][d], p0 = pp[r0][d];
            const float s1 = ss[r1][d], p1 = pp[r1][d];
            a0.x += s0 * w1.x + p0 * w2.x; a0.y += s0 * w1.y + p0 * w2.y;
            a0.z += s0 * w1.z + p0 * w2.z; a0.w += s0 * w1.w + p0 * w2.w;
            a1.x += s1 * w1.x + p1 * w2.x; a1.y += s1 * w1.y + p1 * w2.y;
            a1.z += s1 * w1.z + p1 * w2.z; a1.w += s1 * w1.w + p1 * w2.w;
        }
        const float4 b4 = *reinterpret_cast<const float4*>(&bsum[cg * 4]);
        const int n0 = base + r0, n1 = base + r1;
        if (n0 < N) {
            float4 o = {leaky(a0.x + b4.x), leaky(a0.y + b4.y), leaky(a0.z + b4.z), leaky(a0.w + b4.w)};
            *reinterpret_cast<float4*>(&out[(size_t)n0 * D + cg * 4]) = o;
        }
        if (n1 < N) {
            float4 o = {leaky(a1.x + b4.x), leaky(a1.y + b4.y), leaky(a1.z + b4.z), leaky(a1.w + b4.w)};
            *reinterpret_cast<float4*>(&out[(size_t)n1 * D + cg * 4]) = o;
        }
    }
}

extern "C" void kernel_launch(void* const* d_in, const int* in_sizes, int n_in,
                              void* d_out, int out_size, void* d_ws, size_t ws_size,
                              hipStream_t stream) {
    const int*   idx  = (const int*)d_in[0];   // (2, E) int32
    const float* feat = (const float*)d_in[1]; // (N, 64)
    const float* er   = (const float*)d_in[2]; // (E, 64)
    const float* W1   = (const float*)d_in[4];
    const float* b1   = (const float*)d_in[5];
    const float* W2   = (const float*)d_in[6];
    const float* b2   = (const float*)d_in[7];
    const float* Wa   = (const float*)d_in[8];
    const float* ba   = (const float*)d_in[9];

    const int E = in_sizes[0] / 2;
    const int N = in_sizes[1] / D;
    const int* srcI = idx;
    const int* dstI = idx + E;

    // ws: [hneigh N*64 f32 | htB N*64 bf16 | featB N*64 bf16 | es E int2 | offs N i | partials 256 i]
    float*    hneigh   = (float*)d_ws;
    ushort_t* htB      = (ushort_t*)(hneigh + (size_t)N * D);
    ushort_t* featB    = htB + (size_t)N * D;
    int2*     es       = (int2*)(featB + (size_t)N * D);
    int*      offs     = (int*)(es + E);
    int*      partials = offs + N;

    const int NB = (N + SCAN_CHUNK - 1) / SCAN_CHUNK;

    hipMemsetAsync(offs, 0, (size_t)N * sizeof(int), stream);

    dim3 blk(256);
    k_htrans <<<dim3((N + 63) / 64), blk, 0, stream>>>(feat, Wa, ba, htB, N);
    k_tobf   <<<dim3((N * D / 8 + 255) / 256), blk, 0, stream>>>(feat, featB, N * D / 8);
    k_hist   <<<dim3((E + 255) / 256), blk, 0, stream>>>(dstI, offs, E);
    k_scan1  <<<dim3(NB), blk, 0, stream>>>(offs, partials, N);
    k_scan2  <<<dim3(1), dim3(64), 0, stream>>>(partials, NB);
    k_scan3  <<<dim3(NB), blk, 0, stream>>>(offs, partials, N);
    k_scatter<<<dim3((E + 255) / 256), blk, 0, stream>>>(dstI, srcI, offs, es, E);
    k_fused  <<<dim3((N + 3) / 4), blk, 0, stream>>>(es, offs, htB, er, featB, hneigh, N);
    k_out    <<<dim3((N + 63) / 64), blk, 0, stream>>>(feat, hneigh, W1, b1, W2, b2, (float*)d_out, N);
}